// Round 9
// baseline (215.050 us; speedup 1.0000x reference)
//
#include <hip/hip_runtime.h>
#include <hip/hip_bf16.h>

// Attention: xq/xk/xv [2,2048,768] f32, W* [768,768] f32 ([out,in]), bp [768] f32.
// Pipeline: fused cast->bf16, fused QKV NT-GEMM (scale*log2e folded into Q; V
// computed TRANSPOSED via swapped operands; 128x96/96x128 tiles = 768 blocks),
// flash attention v2: S^T=K*Q^T with K/V loaded GLOBAL->REGISTERS (no LDS
// staging, no mid-loop barriers; LDS only for the P C->B-layout round-trip and
// the end kv-quarter combine; XCD-swizzled so each XCD's L2 holds its 3 heads'
// K/V), output NT-GEMM + bias (f32 out, BK=128).

#define NSEQ 2048
#define CDIM 768
#define NH   12
#define HD   64
#define MTOT 4096            // B*NSEQ
#define XEL  (MTOT*CDIM)     // 3145728
#define WEL  (CDIM*CDIM)     // 589824
#define X8   (XEL/8)         // 393216
#define W8   (WEL/8)         // 73728
#define PSTR 72              // P row stride (shorts): 144B = 16B-aligned
#define QSCALE 0.18033688011112042f   // 0.125 * log2(e); scores consumed by exp2

typedef __attribute__((ext_vector_type(8))) short bf16x8;
typedef __attribute__((ext_vector_type(4))) float floatx4;

// scalar f32->bf16, round-half-up (2 VALU)
static __device__ __forceinline__ unsigned short f2bf(float f) {
  union { float f; unsigned int u; } v; v.f = f;
  return (unsigned short)((v.u + 0x8000u) >> 16);
}
// packed pair f32->bf16x2, round-half-up: 2 v_add + 1 v_perm
static __device__ __forceinline__ unsigned pk2bf(float a, float b) {
  unsigned ua = __float_as_uint(a) + 0x8000u;
  unsigned ub = __float_as_uint(b) + 0x8000u;
  return __builtin_amdgcn_perm(ub, ua, 0x07060302);  // {hi16(b), hi16(a)}
}

static __device__ __forceinline__ void lds16(const void* g, void* l) {
  __builtin_amdgcn_global_load_lds(
      (const __attribute__((address_space(1))) unsigned int*)g,
      (__attribute__((address_space(3))) unsigned int*)l, 16, 0, 0);
}

// ---------------- fused cast f32 -> bf16 (all 7 tensors, one launch) ----------
__global__ __launch_bounds__(256) void cast_all(
    const float* __restrict__ xq, const float* __restrict__ xk,
    const float* __restrict__ xv, const float* __restrict__ wq,
    const float* __restrict__ wk, const float* __restrict__ wv,
    const float* __restrict__ wp,
    unsigned short* __restrict__ Xq, unsigned short* __restrict__ Xk,
    unsigned short* __restrict__ Xv, unsigned short* __restrict__ Wq,
    unsigned short* __restrict__ Wk, unsigned short* __restrict__ Wv,
    unsigned short* __restrict__ Wp) {
  int i = blockIdx.x * 256 + threadIdx.x;
  const float* s; unsigned short* d; int off;
  if (i < 3 * X8) {
    int t = i / X8; off = i - t * X8;
    s = (t == 0) ? xq : (t == 1) ? xk : xv;
    d = (t == 0) ? Xq : (t == 1) ? Xk : Xv;
  } else {
    int j = i - 3 * X8; int t = j / W8; off = j - t * W8;
    s = (t == 0) ? wq : (t == 1) ? wk : (t == 2) ? wv : wp;
    d = (t == 0) ? Wq : (t == 1) ? Wk : (t == 2) ? Wv : Wp;
  }
  const float4* sp = (const float4*)s + (size_t)off * 2;
  float4 a = sp[0], b = sp[1];
  uint4 o;
  o.x = pk2bf(a.x, a.y); o.y = pk2bf(a.z, a.w);
  o.z = pk2bf(b.x, b.y); o.w = pk2bf(b.z, b.w);
  *(uint4*)(d + (size_t)off * 8) = o;
}

// ---------------- fused QKV NT-GEMM: 768 blocks = 3/CU even ----------------
// z=0: Q = Xq Wq^T * QSCALE, tile 128m x 96n ; z=1: K, same tiling;
// z=2: V^T = Wv Xv^T, tile 96(o) x 128(m) (coalesced Vt writes).
__global__ __launch_bounds__(256) void gemm_qkv(
    const unsigned short* __restrict__ Xq, const unsigned short* __restrict__ Xk,
    const unsigned short* __restrict__ Xv, const unsigned short* __restrict__ Wq,
    const unsigned short* __restrict__ Wk, const unsigned short* __restrict__ Wv,
    unsigned short* __restrict__ Qo, unsigned short* __restrict__ Ko,
    unsigned short* __restrict__ Vo) {
  int z = blockIdx.z;
  const unsigned short* A; const unsigned short* B; int am0, bn0, RA;
  if (z == 0)      { A = Xq; B = Wq; am0 = blockIdx.y * 128; bn0 = blockIdx.x * 96; RA = 128; }
  else if (z == 1) { A = Xk; B = Wk; am0 = blockIdx.y * 128; bn0 = blockIdx.x * 96; RA = 128; }
  else             { A = Wv; B = Xv; am0 = blockIdx.x * 96;  bn0 = blockIdx.y * 128; RA = 96; }
  __shared__ __align__(16) unsigned short S[224 * 64];
  int tid = threadIdx.x, lane = tid & 63, wave = tid >> 6;
  int quad = lane >> 4, l15 = lane & 15, l7 = l15 & 7;

  const unsigned short* gptr[7]; int ldo[7];
#pragma unroll
  for (int i = 0; i < 7; i++) {
    int idx = i * 256 + tid;
    int row = idx >> 3, c = (idx & 7) ^ (row & 7);
    gptr[i] = (row < RA ? A + (size_t)(am0 + row) * CDIM
                        : B + (size_t)(bn0 + row - RA) * CDIM) + c * 8;
    ldo[i] = idx * 8;
  }
  floatx4 acc[12];
#pragma unroll
  for (int i = 0; i < 12; i++) acc[i] = (floatx4){0.f, 0.f, 0.f, 0.f};

  for (int k0 = 0; k0 < CDIM; k0 += 64) {
#pragma unroll
    for (int i = 0; i < 7; i++) lds16(gptr[i] + k0, &S[ldo[i]]);
    __syncthreads();
    if (z < 2) {
      int wm = (wave >> 1) * 64, wn = (wave & 1) * 48;
#pragma unroll
      for (int ks = 0; ks < 2; ks++) {
        int csw = ((ks * 4 + quad) ^ l7) * 8;
        bf16x8 af[4], bfr[3];
#pragma unroll
        for (int i = 0; i < 4; i++)
          af[i] = *(const bf16x8*)&S[(wm + i * 16 + l15) * 64 + csw];
#pragma unroll
        for (int j = 0; j < 3; j++)
          bfr[j] = *(const bf16x8*)&S[(128 + wn + j * 16 + l15) * 64 + csw];
#pragma unroll
        for (int mi = 0; mi < 4; mi++)
#pragma unroll
          for (int ni = 0; ni < 3; ni++)
            acc[mi * 3 + ni] = __builtin_amdgcn_mfma_f32_16x16x32_bf16(
                af[mi], bfr[ni], acc[mi * 3 + ni], 0, 0, 0);
      }
    } else {
      int wm = (wave & 1) * 48, wn = (wave >> 1) * 64;
#pragma unroll
      for (int ks = 0; ks < 2; ks++) {
        int csw = ((ks * 4 + quad) ^ l7) * 8;
        bf16x8 af[3], bfr[4];
#pragma unroll
        for (int i = 0; i < 3; i++)
          af[i] = *(const bf16x8*)&S[(wm + i * 16 + l15) * 64 + csw];
#pragma unroll
        for (int j = 0; j < 4; j++)
          bfr[j] = *(const bf16x8*)&S[(96 + wn + j * 16 + l15) * 64 + csw];
#pragma unroll
        for (int mi = 0; mi < 3; mi++)
#pragma unroll
          for (int ni = 0; ni < 4; ni++)
            acc[mi * 4 + ni] = __builtin_amdgcn_mfma_f32_16x16x32_bf16(
                af[mi], bfr[ni], acc[mi * 4 + ni], 0, 0, 0);
      }
    }
    __syncthreads();
  }
  if (z < 2) {
    int wm = (wave >> 1) * 64, wn = (wave & 1) * 48;
#pragma unroll
    for (int mi = 0; mi < 4; mi++)
#pragma unroll
      for (int ni = 0; ni < 3; ni++)
#pragma unroll
        for (int r = 0; r < 4; r++) {
          int grow = am0 + wm + mi * 16 + quad * 4 + r;
          int gcol = bn0 + wn + ni * 16 + l15;
          float v = acc[mi * 3 + ni][r];
          int b = grow >> 11, nq = grow & 2047, h = gcol >> 6, dd = gcol & 63;
          if (z == 0)
            Qo[((size_t)(b * NH + h) * NSEQ + nq) * HD + dd] = f2bf(v * QSCALE);
          else
            Ko[((size_t)(b * NH + h) * NSEQ + nq) * HD + dd] = f2bf(v);
        }
  } else {
    int wm = (wave & 1) * 48, wn = (wave >> 1) * 64;
#pragma unroll
    for (int mi = 0; mi < 3; mi++)
#pragma unroll
      for (int ni = 0; ni < 4; ni++)
#pragma unroll
        for (int r = 0; r < 4; r++) {
          int o = am0 + wm + mi * 16 + quad * 4 + r;
          int mg = bn0 + wn + ni * 16 + l15;
          int b = mg >> 11, nq = mg & 2047;
          Vo[((size_t)b * CDIM + o) * NSEQ + nq] = f2bf(acc[mi * 4 + ni][r]);
        }
  }
}

// ---------------- flash attention v2: global->register K/V, no staging ------
// Q,K: [24][2048][64] bf16 (Q pre-scaled); Vt: [24][64][2048] bf16.
// ctx: [4096][768] bf16. 768 blocks x 256 thr; block = (bh, 64 q rows);
// wave = kv-quarter (512 kv). XCD swizzle: bh = (blk&7)*3 + (blk>>3)/32 so each
// XCD's L2 holds only its 3 heads' K/V (1.5 MB < 4 MB). No mid-loop barriers:
// P round-trip is wave-private LDS; kv-quarter partials combined at the end
// (max-free softmax sums exactly). lacc via VALU (frees AGPR/VGPR budget).
__global__ __launch_bounds__(256, 3) void attn_kernel(
    const unsigned short* __restrict__ Q, const unsigned short* __restrict__ K,
    const unsigned short* __restrict__ Vt, unsigned short* __restrict__ ctx) {
  int n = blockIdx.x;
  int g = n >> 3;
  int bh = (n & 7) * 3 + (g >> 5);
  int qt = g & 31;
  int tid = threadIdx.x, lane = tid & 63, wave = tid >> 6;
  int quad = lane >> 4, l15 = lane & 15;
  __shared__ __align__(16) unsigned short SH[4 * 64 * PSTR];  // 36864 B

  const unsigned short* Qg = Q + ((size_t)bh * NSEQ + qt * 64) * HD;
  const unsigned short* Kg = K + ((size_t)bh * NSEQ + wave * 512) * HD;
  const unsigned short* Vg = Vt + (size_t)bh * HD * NSEQ + wave * 512;

  // Q fragments (B-operand), 64 q rows per wave, in registers
  bf16x8 qf[4][2];
#pragma unroll
  for (int qi = 0; qi < 4; qi++)
#pragma unroll
    for (int ks = 0; ks < 2; ks++)
      qf[qi][ks] = *(const bf16x8*)(Qg + (qi * 16 + l15) * HD + ks * 32 + quad * 8);

  unsigned short* Pw = &SH[wave * 64 * PSTR];
  float lacc[4] = {0.f, 0.f, 0.f, 0.f};
  floatx4 o[4][4];
#pragma unroll
  for (int qi = 0; qi < 4; qi++)
#pragma unroll
    for (int dt = 0; dt < 4; dt++) o[qi][dt] = (floatx4){0.f, 0.f, 0.f, 0.f};

  for (int t = 0; t < 8; t++) {
    const unsigned short* Kt = Kg + t * 64 * HD;
    const unsigned short* Vp = Vg + t * 64;
    // K fragments global->reg (A-operand: m=kv, k=d)
    bf16x8 kf[4][2];
#pragma unroll
    for (int nt = 0; nt < 4; nt++)
#pragma unroll
      for (int x = 0; x < 2; x++)
        kf[nt][x] = *(const bf16x8*)(Kt + (nt * 16 + l15) * HD + x * 32 + quad * 8);
    // S^T = K Q^T -> exp2 -> P (wave-private LDS, [q][kv] layout)
#pragma unroll
    for (int qi = 0; qi < 4; qi++)
#pragma unroll
      for (int nt = 0; nt < 4; nt++) {
        floatx4 st = (floatx4){0.f, 0.f, 0.f, 0.f};
        st = __builtin_amdgcn_mfma_f32_16x16x32_bf16(kf[nt][0], qf[qi][0], st, 0, 0, 0);
        st = __builtin_amdgcn_mfma_f32_16x16x32_bf16(kf[nt][1], qf[qi][1], st, 0, 0, 0);
        float p0 = __builtin_exp2f(st[0]), p1 = __builtin_exp2f(st[1]);
        float p2 = __builtin_exp2f(st[2]), p3 = __builtin_exp2f(st[3]);
        lacc[qi] += (p0 + p1) + (p2 + p3);
        *(uint2*)&Pw[(qi * 16 + l15) * PSTR + nt * 16 + quad * 4] =
            make_uint2(pk2bf(p0, p1), pk2bf(p2, p3));
      }
    // V fragments global->reg (A-operand: m=d, k=kv); kf regs dead -> reused
    bf16x8 vf[4][2];
#pragma unroll
    for (int dt = 0; dt < 4; dt++)
#pragma unroll
      for (int x = 0; x < 2; x++)
        vf[dt][x] = *(const bf16x8*)(Vp + (dt * 16 + l15) * NSEQ + x * 32 + quad * 8);
    // O^T += Vt P^T
#pragma unroll
    for (int qi = 0; qi < 4; qi++)
#pragma unroll
      for (int ks = 0; ks < 2; ks++) {
        bf16x8 pf = *(const bf16x8*)&Pw[(qi * 16 + l15) * PSTR + ks * 32 + quad * 8];
#pragma unroll
        for (int dt = 0; dt < 4; dt++)
          o[qi][dt] = __builtin_amdgcn_mfma_f32_16x16x32_bf16(vf[dt][ks], pf, o[qi][dt], 0, 0, 0);
      }
  }
  // reduce lacc across the 4 quads holding the same q
#pragma unroll
  for (int qi = 0; qi < 4; qi++) {
    lacc[qi] += __shfl_xor(lacc[qi], 16, 64);
    lacc[qi] += __shfl_xor(lacc[qi], 32, 64);
  }
  // kv-quarter combine through LDS (P regions dead after this barrier)
  float* Ob0 = (float*)&SH[0];       // 64q x 64d f32 = 16 KB
  float* Ob1 = (float*)&SH[8192];
  float* Lb0 = (float*)&SH[16384];   // 64 f32
  float* Lb1 = (float*)&SH[16512];
  __syncthreads();
  if (wave == 1 || wave == 3) {
    float* Ob = (wave == 1) ? Ob0 : Ob1;
    float* Lb = (wave == 1) ? Lb0 : Lb1;
#pragma unroll
    for (int qi = 0; qi < 4; qi++) {
      int ro = qi * 16 + l15;
#pragma unroll
      for (int dt = 0; dt < 4; dt++)
        *(floatx4*)&Ob[ro * 64 + dt * 16 + quad * 4] = o[qi][dt];
      if (quad == 0) Lb[ro] = lacc[qi];
    }
  }
  __syncthreads();
  if (wave == 0 || wave == 2) {
    float* Ob = (wave == 0) ? Ob0 : Ob1;
    float* Lb = (wave == 0) ? Lb0 : Lb1;
#pragma unroll
    for (int qi = 0; qi < 4; qi++) {
      int ro = qi * 16 + l15;
#pragma unroll
      for (int dt = 0; dt < 4; dt++) {
        floatx4 ob = *(floatx4*)&Ob[ro * 64 + dt * 16 + quad * 4];
        o[qi][dt][0] += ob[0]; o[qi][dt][1] += ob[1];
        o[qi][dt][2] += ob[2]; o[qi][dt][3] += ob[3];
      }
      lacc[qi] += Lb[ro];
    }
  }
  __syncthreads();
  if (wave == 2) {
#pragma unroll
    for (int qi = 0; qi < 4; qi++) {
      int ro = qi * 16 + l15;
#pragma unroll
      for (int dt = 0; dt < 4; dt++)
        *(floatx4*)&Ob0[ro * 64 + dt * 16 + quad * 4] = o[qi][dt];
      if (quad == 0) Lb0[ro] = lacc[qi];
    }
  }
  __syncthreads();
  if (wave == 0) {
    int b = bh / NH, h = bh - b * NH;
#pragma unroll
    for (int qi = 0; qi < 4; qi++) {
      int ro = qi * 16 + l15;
      float inv = 1.f / (lacc[qi] + Lb0[ro]);
      int qrow = qt * 64 + ro;
      size_t gbase = (size_t)(b * NSEQ + qrow) * CDIM + h * HD + quad * 4;
#pragma unroll
      for (int dt = 0; dt < 4; dt++) {
        floatx4 ob = *(floatx4*)&Ob0[ro * 64 + dt * 16 + quad * 4];
        float v0 = (o[qi][dt][0] + ob[0]) * inv, v1 = (o[qi][dt][1] + ob[1]) * inv;
        float v2 = (o[qi][dt][2] + ob[2]) * inv, v3 = (o[qi][dt][3] + ob[3]) * inv;
        *(uint2*)&ctx[gbase + dt * 16] = make_uint2(pk2bf(v0, v1), pk2bf(v2, v3));
      }
    }
  }
}

// ---------------- output NT-GEMM + bias, 64x64 tiles, BK=128, f32 out --------
__global__ __launch_bounds__(256) void gemm_out(
    const unsigned short* __restrict__ A, const unsigned short* __restrict__ B,
    const float* __restrict__ bias, float* __restrict__ out) {
  int m0 = blockIdx.y * 64, n0 = blockIdx.x * 64;
  __shared__ __align__(16) unsigned short As[64 * 128];
  __shared__ __align__(16) unsigned short Bs[64 * 128];
  int tid = threadIdx.x, lane = tid & 63, wave = tid >> 6;
  int quad = lane >> 4, l15 = lane & 15, l7 = l15 & 7;
  int wm = (wave >> 1) * 32, wn = (wave & 1) * 32;
  floatx4 acc[2][2];
#pragma unroll
  for (int i = 0; i < 2; i++)
#pragma unroll
    for (int j = 0; j < 2; j++) acc[i][j] = (floatx4){0.f, 0.f, 0.f, 0.f};

  for (int k0 = 0; k0 < CDIM; k0 += 128) {
#pragma unroll
    for (int i = 0; i < 4; i++) {
      int idx = i * 256 + tid;
      int R = idx >> 4, c4 = idx & 15;
      int cs = (c4 & 8) | ((c4 & 7) ^ (R & 7));
      lds16(A + (size_t)(m0 + R) * CDIM + k0 + cs * 8, &As[idx * 8]);
      lds16(B + (size_t)(n0 + R) * CDIM + k0 + cs * 8, &Bs[idx * 8]);
    }
    __syncthreads();
#pragma unroll
    for (int ks = 0; ks < 4; ks++) {
      int c = ks * 4 + quad;
      int csw = ((c & 8) | ((c & 7) ^ l7)) * 8;
      bf16x8 af[2], bfr[2];
#pragma unroll
      for (int i = 0; i < 2; i++)
        af[i] = *(const bf16x8*)&As[(wm + i * 16 + l15) * 128 + csw];
#pragma unroll
      for (int i = 0; i < 2; i++)
        bfr[i] = *(const bf16x8*)&Bs[(wn + i * 16 + l15) * 128 + csw];
#pragma unroll
      for (int mi = 0; mi < 2; mi++)
#pragma unroll
        for (int ni = 0; ni < 2; ni++)
          acc[mi][ni] = __builtin_amdgcn_mfma_f32_16x16x32_bf16(
              af[mi], bfr[ni], acc[mi][ni], 0, 0, 0);
    }
    __syncthreads();
  }
  float bv[2];
#pragma unroll
  for (int ni = 0; ni < 2; ni++) bv[ni] = bias[n0 + wn + ni * 16 + l15];
#pragma unroll
  for (int mi = 0; mi < 2; mi++)
#pragma unroll
    for (int ni = 0; ni < 2; ni++)
#pragma unroll
      for (int r = 0; r < 4; r++) {
        int grow = m0 + wm + mi * 16 + quad * 4 + r;
        int gcol = n0 + wn + ni * 16 + l15;
        out[(size_t)grow * CDIM + gcol] = acc[mi][ni][r] + bv[ni];
      }
}

extern "C" void kernel_launch(void* const* d_in, const int* in_sizes, int n_in,
                              void* d_out, int out_size, void* d_ws, size_t ws_size,
                              hipStream_t stream) {
  const float* xq = (const float*)d_in[0];
  const float* xk = (const float*)d_in[1];
  const float* xv = (const float*)d_in[2];
  const float* wq = (const float*)d_in[3];
  const float* wk = (const float*)d_in[4];
  const float* wv = (const float*)d_in[5];
  const float* wp = (const float*)d_in[6];
  const float* bp = (const float*)d_in[7];
  float* out = (float*)d_out;

  char* p = (char*)d_ws;
  unsigned short* Xq = (unsigned short*)p; p += (size_t)XEL * 2;
  unsigned short* Xk = (unsigned short*)p; p += (size_t)XEL * 2;
  unsigned short* Xv = (unsigned short*)p; p += (size_t)XEL * 2;
  unsigned short* Wq = (unsigned short*)p; p += (size_t)WEL * 2;
  unsigned short* Wk = (unsigned short*)p; p += (size_t)WEL * 2;
  unsigned short* Wv = (unsigned short*)p; p += (size_t)WEL * 2;
  unsigned short* Wp = (unsigned short*)p; p += (size_t)WEL * 2;
  unsigned short* Qb = (unsigned short*)p; p += (size_t)XEL * 2;
  unsigned short* Kb = (unsigned short*)p; p += (size_t)XEL * 2;
  unsigned short* Vb = (unsigned short*)p; p += (size_t)XEL * 2;
  unsigned short* Cx = (unsigned short*)p; p += (size_t)XEL * 2;

  cast_all<<<(3 * X8 + 4 * W8) / 256, 256, 0, stream>>>(
      xq, xk, xv, wq, wk, wv, wp, Xq, Xk, Xv, Wq, Wk, Wv, Wp);

  gemm_qkv<<<dim3(8, 32, 3), 256, 0, stream>>>(
      Xq, Xk, Xv, Wq, Wk, Wv, Qb, Kb, Vb);

  attn_kernel<<<768, 256, 0, stream>>>(Qb, Kb, Vb, Cx);

  gemm_out<<<dim3(CDIM / 64, MTOT / 64), 256, 0, stream>>>(Cx, Wp, bp, out);
}

// Round 10
// 186.238 us; speedup vs baseline: 1.1547x; 1.1547x over previous
//
#include <hip/hip_runtime.h>
#include <hip/hip_bf16.h>

// Attention: xq/xk/xv [2,2048,768] f32, W* [768,768] f32 ([out,in]), bp [768] f32.
// Pipeline: fused cast->bf16, fused QKV NT-GEMM (scale*log2e folded into Q; V
// computed TRANSPOSED via swapped operands; XCD-swizzled blocks), flash attention
// (r8 structure: LDS-staged K/V, S^T=K*Q^T, max-free softmax via exp2, in-block
// kv-split, l on MFMA pipe; XCD-swizzled so each XCD's L2 holds 3 heads' K/V),
// output NT-GEMM + bias (64x96 tiles, BK=128, f32 out). LDS XOR-swizzled.

#define NSEQ 2048
#define CDIM 768
#define NH   12
#define HD   64
#define MTOT 4096            // B*NSEQ
#define XEL  (MTOT*CDIM)     // 3145728
#define WEL  (CDIM*CDIM)     // 589824
#define X8   (XEL/8)         // 393216
#define W8   (WEL/8)         // 73728
#define PSTR 72              // P row stride (shorts): 144B = 16B-aligned
#define QSCALE 0.18033688011112042f   // 0.125 * log2(e); scores consumed by exp2

typedef __attribute__((ext_vector_type(8))) short bf16x8;
typedef __attribute__((ext_vector_type(4))) float floatx4;

// scalar f32->bf16, round-half-up (2 VALU)
static __device__ __forceinline__ unsigned short f2bf(float f) {
  union { float f; unsigned int u; } v; v.f = f;
  return (unsigned short)((v.u + 0x8000u) >> 16);
}
// packed pair f32->bf16x2, round-half-up: 2 v_add + 1 v_perm
static __device__ __forceinline__ unsigned pk2bf(float a, float b) {
  unsigned ua = __float_as_uint(a) + 0x8000u;
  unsigned ub = __float_as_uint(b) + 0x8000u;
  return __builtin_amdgcn_perm(ub, ua, 0x07060302);  // {hi16(b), hi16(a)}
}

static __device__ __forceinline__ void lds16(const void* g, void* l) {
  __builtin_amdgcn_global_load_lds(
      (const __attribute__((address_space(1))) unsigned int*)g,
      (__attribute__((address_space(3))) unsigned int*)l, 16, 0, 0);
}

// ---------------- fused cast f32 -> bf16 (all 7 tensors, one launch) ----------
__global__ __launch_bounds__(256) void cast_all(
    const float* __restrict__ xq, const float* __restrict__ xk,
    const float* __restrict__ xv, const float* __restrict__ wq,
    const float* __restrict__ wk, const float* __restrict__ wv,
    const float* __restrict__ wp,
    unsigned short* __restrict__ Xq, unsigned short* __restrict__ Xk,
    unsigned short* __restrict__ Xv, unsigned short* __restrict__ Wq,
    unsigned short* __restrict__ Wk, unsigned short* __restrict__ Wv,
    unsigned short* __restrict__ Wp) {
  int i = blockIdx.x * 256 + threadIdx.x;
  const float* s; unsigned short* d; int off;
  if (i < 3 * X8) {
    int t = i / X8; off = i - t * X8;
    s = (t == 0) ? xq : (t == 1) ? xk : xv;
    d = (t == 0) ? Xq : (t == 1) ? Xk : Xv;
  } else {
    int j = i - 3 * X8; int t = j / W8; off = j - t * W8;
    s = (t == 0) ? wq : (t == 1) ? wk : (t == 2) ? wv : wp;
    d = (t == 0) ? Wq : (t == 1) ? Wk : (t == 2) ? Wv : Wp;
  }
  const float4* sp = (const float4*)s + (size_t)off * 2;
  float4 a = sp[0], b = sp[1];
  uint4 o;
  o.x = pk2bf(a.x, a.y); o.y = pk2bf(a.z, a.w);
  o.z = pk2bf(b.x, b.y); o.w = pk2bf(b.z, b.w);
  *(uint4*)(d + (size_t)off * 8) = o;
}

// ---------------- fused QKV NT-GEMM: 768 blocks, XCD-swizzled ----------------
// z=0: Q = Xq Wq^T * QSCALE, tile 128m x 96n ; z=1: K, same tiling;
// z=2: V^T = Wv Xv^T, tile 96(o) x 128(m) (coalesced Vt writes).
// Block decode: XCD (blk%8) owns 4 m-slabs x all n-tiles x all z -> A/B slabs
// mostly L2-resident per XCD.
__global__ __launch_bounds__(256) void gemm_qkv(
    const unsigned short* __restrict__ Xq, const unsigned short* __restrict__ Xk,
    const unsigned short* __restrict__ Xv, const unsigned short* __restrict__ Wq,
    const unsigned short* __restrict__ Wk, const unsigned short* __restrict__ Wv,
    unsigned short* __restrict__ Qo, unsigned short* __restrict__ Ko,
    unsigned short* __restrict__ Vo) {
  int i0 = blockIdx.x;
  int mg = i0 & 7; int t0 = i0 >> 3;       // t0 in [0,96)
  int z = t0 % 3; int u = t0 / 3;          // u in [0,32)
  int xn = u & 7, ysub = u >> 3;           // 8 n-tiles x 4 m-subtiles
  int y = mg * 4 + ysub;                   // m-tile in [0,32)
  const unsigned short* A; const unsigned short* B; int am0, bn0, RA;
  if (z == 0)      { A = Xq; B = Wq; am0 = y * 128; bn0 = xn * 96; RA = 128; }
  else if (z == 1) { A = Xk; B = Wk; am0 = y * 128; bn0 = xn * 96; RA = 128; }
  else             { A = Wv; B = Xv; am0 = xn * 96; bn0 = y * 128; RA = 96; }
  __shared__ __align__(16) unsigned short S[224 * 64];
  int tid = threadIdx.x, lane = tid & 63, wave = tid >> 6;
  int quad = lane >> 4, l15 = lane & 15, l7 = l15 & 7;

  const unsigned short* gptr[7]; int ldo[7];
#pragma unroll
  for (int i = 0; i < 7; i++) {
    int idx = i * 256 + tid;
    int row = idx >> 3, c = (idx & 7) ^ (row & 7);
    gptr[i] = (row < RA ? A + (size_t)(am0 + row) * CDIM
                        : B + (size_t)(bn0 + row - RA) * CDIM) + c * 8;
    ldo[i] = idx * 8;
  }
  floatx4 acc[12];
#pragma unroll
  for (int i = 0; i < 12; i++) acc[i] = (floatx4){0.f, 0.f, 0.f, 0.f};

  for (int k0 = 0; k0 < CDIM; k0 += 64) {
#pragma unroll
    for (int i = 0; i < 7; i++) lds16(gptr[i] + k0, &S[ldo[i]]);
    __syncthreads();
    if (z < 2) {
      int wm = (wave >> 1) * 64, wn = (wave & 1) * 48;
#pragma unroll
      for (int ks = 0; ks < 2; ks++) {
        int csw = ((ks * 4 + quad) ^ l7) * 8;
        bf16x8 af[4], bfr[3];
#pragma unroll
        for (int i = 0; i < 4; i++)
          af[i] = *(const bf16x8*)&S[(wm + i * 16 + l15) * 64 + csw];
#pragma unroll
        for (int j = 0; j < 3; j++)
          bfr[j] = *(const bf16x8*)&S[(128 + wn + j * 16 + l15) * 64 + csw];
#pragma unroll
        for (int mi = 0; mi < 4; mi++)
#pragma unroll
          for (int ni = 0; ni < 3; ni++)
            acc[mi * 3 + ni] = __builtin_amdgcn_mfma_f32_16x16x32_bf16(
                af[mi], bfr[ni], acc[mi * 3 + ni], 0, 0, 0);
      }
    } else {
      int wm = (wave & 1) * 48, wn = (wave >> 1) * 64;
#pragma unroll
      for (int ks = 0; ks < 2; ks++) {
        int csw = ((ks * 4 + quad) ^ l7) * 8;
        bf16x8 af[3], bfr[4];
#pragma unroll
        for (int i = 0; i < 3; i++)
          af[i] = *(const bf16x8*)&S[(wm + i * 16 + l15) * 64 + csw];
#pragma unroll
        for (int j = 0; j < 4; j++)
          bfr[j] = *(const bf16x8*)&S[(96 + wn + j * 16 + l15) * 64 + csw];
#pragma unroll
        for (int mi = 0; mi < 3; mi++)
#pragma unroll
          for (int ni = 0; ni < 4; ni++)
            acc[mi * 4 + ni] = __builtin_amdgcn_mfma_f32_16x16x32_bf16(
                af[mi], bfr[ni], acc[mi * 4 + ni], 0, 0, 0);
      }
    }
    __syncthreads();
  }
  if (z < 2) {
    int wm = (wave >> 1) * 64, wn = (wave & 1) * 48;
#pragma unroll
    for (int mi = 0; mi < 4; mi++)
#pragma unroll
      for (int ni = 0; ni < 3; ni++)
#pragma unroll
        for (int r = 0; r < 4; r++) {
          int grow = am0 + wm + mi * 16 + quad * 4 + r;
          int gcol = bn0 + wn + ni * 16 + l15;
          float v = acc[mi * 3 + ni][r];
          int b = grow >> 11, nq = grow & 2047, h = gcol >> 6, dd = gcol & 63;
          if (z == 0)
            Qo[((size_t)(b * NH + h) * NSEQ + nq) * HD + dd] = f2bf(v * QSCALE);
          else
            Ko[((size_t)(b * NH + h) * NSEQ + nq) * HD + dd] = f2bf(v);
        }
  } else {
    int wm = (wave & 1) * 48, wn = (wave >> 1) * 64;
#pragma unroll
    for (int mi = 0; mi < 3; mi++)
#pragma unroll
      for (int ni = 0; ni < 4; ni++)
#pragma unroll
        for (int r = 0; r < 4; r++) {
          int o = am0 + wm + mi * 16 + quad * 4 + r;
          int mgl = bn0 + wn + ni * 16 + l15;
          int b = mgl >> 11, nq = mgl & 2047;
          Vo[((size_t)b * CDIM + o) * NSEQ + nq] = f2bf(acc[mi * 4 + ni][r]);
        }
  }
}

// ---------------- flash attention: r8 structure + XCD swizzle ----------------
// Q,K: [24][2048][64] bf16 (Q pre-scaled); Vt: [24][64][2048] bf16.
// ctx: [4096][768] bf16. 768 blocks x 256 thr = 4 waves:
//   wave = (half<<1)|qsub: qsub selects 32 q-rows, half selects kv range.
// Block decode: bh = (blk%8)*3 + ... so each XCD's L2 holds its 3 heads' K/V.
// l accumulated on the MFMA pipe (ones-fragment). Max-free softmax => kv-partials
// combine exactly through LDS.
__global__ __launch_bounds__(256, 3) void attn_kernel(
    const unsigned short* __restrict__ Q, const unsigned short* __restrict__ K,
    const unsigned short* __restrict__ Vt, unsigned short* __restrict__ ctx) {
  int i0 = blockIdx.x;
  int xcd = i0 & 7; int t0 = i0 >> 3;
  int bh = xcd * 3 + (t0 >> 5);
  int qt = t0 & 31;
  int tid = threadIdx.x, lane = tid & 63, wave = tid >> 6;
  int half = wave >> 1, qsub = wave & 1;
  int quad = lane >> 4, l15 = lane & 15, l7 = l15 & 7;
  __shared__ __align__(16) unsigned short Ks[2][64 * 64];
  __shared__ __align__(16) unsigned short Vs[2][64 * 64];
  __shared__ __align__(16) unsigned short Ps[4][16 * PSTR];

  const unsigned short* Qg = Q + ((size_t)bh * NSEQ + qt * 64 + qsub * 32) * HD;
  const unsigned short* Kg = K + ((size_t)bh * NSEQ + half * 1024) * HD;
  const unsigned short* Vg = Vt + (size_t)bh * HD * NSEQ + half * 1024;

  bf16x8 qf[2][2];
#pragma unroll
  for (int qi = 0; qi < 2; qi++)
#pragma unroll
    for (int ks = 0; ks < 2; ks++)
      qf[qi][ks] = *(const bf16x8*)(Qg + (qi * 16 + l15) * HD + ks * 32 + quad * 8);

  bf16x8 ones;
#pragma unroll
  for (int i = 0; i < 8; i++) ones[i] = (short)0x3F80;  // bf16 1.0

  int tid2 = tid & 127;
  int kgo[4], vgo[4], ldst[4];
#pragma unroll
  for (int i = 0; i < 4; i++) {
    int idx = i * 128 + tid2;
    int R = idx >> 3, c = (idx & 7) ^ (R & 7);
    kgo[i] = R * HD + c * 8;
    vgo[i] = R * NSEQ + c * 8;
    ldst[i] = idx * 8;
  }
  unsigned short* Ksh = Ks[half];
  unsigned short* Vsh = Vs[half];
  unsigned short* Pw = &Ps[wave][0];

  floatx4 ol[2];
  floatx4 o[2][4];
#pragma unroll
  for (int qi = 0; qi < 2; qi++) {
    ol[qi] = (floatx4){0.f, 0.f, 0.f, 0.f};
#pragma unroll
    for (int dt = 0; dt < 4; dt++) o[qi][dt] = (floatx4){0.f, 0.f, 0.f, 0.f};
  }

  for (int t = 0; t < 16; t++) {
    int k0 = t * 64;
#pragma unroll
    for (int i = 0; i < 4; i++) {
      lds16(Kg + (size_t)k0 * HD + kgo[i], &Ksh[ldst[i]]);
      lds16(Vg + k0 + vgo[i], &Vsh[ldst[i]]);
    }
    __syncthreads();
    bf16x8 kf[4][2], vf[4][2];
#pragma unroll
    for (int nt = 0; nt < 4; nt++)
#pragma unroll
      for (int x = 0; x < 2; x++)
        kf[nt][x] = *(const bf16x8*)&Ksh[(nt * 16 + l15) * 64 + ((x * 4 + quad) ^ l7) * 8];
#pragma unroll
    for (int dt = 0; dt < 4; dt++)
#pragma unroll
      for (int x = 0; x < 2; x++)
        vf[dt][x] = *(const bf16x8*)&Vsh[(dt * 16 + l15) * 64 + ((x * 4 + quad) ^ l7) * 8];
#pragma unroll
    for (int qi = 0; qi < 2; qi++) {
      // S^T = K Q^T: rows kv=nt*16+quad*4+r, col q=l15
#pragma unroll
      for (int nt = 0; nt < 4; nt++) {
        floatx4 st = (floatx4){0.f, 0.f, 0.f, 0.f};
        st = __builtin_amdgcn_mfma_f32_16x16x32_bf16(kf[nt][0], qf[qi][0], st, 0, 0, 0);
        st = __builtin_amdgcn_mfma_f32_16x16x32_bf16(kf[nt][1], qf[qi][1], st, 0, 0, 0);
        float p0 = __builtin_exp2f(st[0]), p1 = __builtin_exp2f(st[1]);
        float p2 = __builtin_exp2f(st[2]), p3 = __builtin_exp2f(st[3]);
        *(uint2*)&Pw[l15 * PSTR + nt * 16 + quad * 4] =
            make_uint2(pk2bf(p0, p1), pk2bf(p2, p3));
      }
      // O^T += Vt P^T; l += ones x P (matrix pipe)
#pragma unroll
      for (int ks = 0; ks < 2; ks++) {
        bf16x8 pf = *(const bf16x8*)&Pw[l15 * PSTR + ks * 32 + quad * 8];
        ol[qi] = __builtin_amdgcn_mfma_f32_16x16x32_bf16(ones, pf, ol[qi], 0, 0, 0);
#pragma unroll
        for (int dt = 0; dt < 4; dt++)
          o[qi][dt] = __builtin_amdgcn_mfma_f32_16x16x32_bf16(vf[dt][ks], pf, o[qi][dt], 0, 0, 0);
      }
    }
    __syncthreads();
  }
  // in-block kv-partial combine: half-1 -> LDS, half-0 adds + stores
  float* Obuf = (float*)&Ks[0][0];   // 64q x 64d f32 = 16 KB
  float* Lbuf = (float*)&Ps[0][0];   // 64 floats
  if (half == 1) {
#pragma unroll
    for (int qi = 0; qi < 2; qi++) {
      int ro = qsub * 32 + qi * 16 + l15;
#pragma unroll
      for (int dt = 0; dt < 4; dt++)
        *(floatx4*)&Obuf[ro * 64 + dt * 16 + quad * 4] = o[qi][dt];
      if (quad == 0) Lbuf[ro] = ol[qi][0];
    }
  }
  __syncthreads();
  if (half == 0) {
    int b = bh / NH, h = bh - b * NH;
#pragma unroll
    for (int qi = 0; qi < 2; qi++) {
      int ro = qsub * 32 + qi * 16 + l15;
      float inv = 1.f / (ol[qi][0] + Lbuf[ro]);
      int qrow = qt * 64 + ro;
      size_t gbase = (size_t)(b * NSEQ + qrow) * CDIM + h * HD + quad * 4;
#pragma unroll
      for (int dt = 0; dt < 4; dt++) {
        floatx4 ob = *(floatx4*)&Obuf[ro * 64 + dt * 16 + quad * 4];
        float v0 = (o[qi][dt][0] + ob[0]) * inv, v1 = (o[qi][dt][1] + ob[1]) * inv;
        float v2 = (o[qi][dt][2] + ob[2]) * inv, v3 = (o[qi][dt][3] + ob[3]) * inv;
        *(uint2*)&ctx[gbase + dt * 16] = make_uint2(pk2bf(v0, v1), pk2bf(v2, v3));
      }
    }
  }
}

// ------------- output NT-GEMM + bias, 64x96 tiles, BK=128, XCD-swizzled ------
__global__ __launch_bounds__(256) void gemm_out(
    const unsigned short* __restrict__ A, const unsigned short* __restrict__ B,
    const float* __restrict__ bias, float* __restrict__ out) {
  int i0 = blockIdx.x;                  // 512 blocks = 2/CU
  int mg = i0 & 7; int t0 = i0 >> 3;    // t0 in [0,64)
  int n0 = (t0 & 7) * 96;
  int m0 = (mg * 8 + (t0 >> 3)) * 64;
  __shared__ __align__(16) unsigned short S[160 * 128];  // A rows 0..63, B rows 64..159
  int tid = threadIdx.x, lane = tid & 63, wave = tid >> 6;
  int quad = lane >> 4, l15 = lane & 15, l7 = l15 & 7;
  int wm = (wave >> 1) * 32, wn = (wave & 1) * 48;
  floatx4 acc[6];
#pragma unroll
  for (int i = 0; i < 6; i++) acc[i] = (floatx4){0.f, 0.f, 0.f, 0.f};

  for (int k0 = 0; k0 < CDIM; k0 += 128) {
#pragma unroll
    for (int i = 0; i < 10; i++) {       // 160 rows x 16 chunks = 2560 = 10*256
      int idx = i * 256 + tid;
      int R = idx >> 4, c4 = idx & 15;
      int cs = (c4 & 8) | ((c4 & 7) ^ (R & 7));
      const unsigned short* g = (R < 64)
          ? A + (size_t)(m0 + R) * CDIM : B + (size_t)(n0 + R - 64) * CDIM;
      lds16(g + k0 + cs * 8, &S[idx * 8]);
    }
    __syncthreads();
#pragma unroll
    for (int ks = 0; ks < 4; ks++) {
      int c = ks * 4 + quad;
      int csw = ((c & 8) | ((c & 7) ^ l7)) * 8;
      bf16x8 af[2], bfr[3];
#pragma unroll
      for (int i = 0; i < 2; i++)
        af[i] = *(const bf16x8*)&S[(wm + i * 16 + l15) * 128 + csw];
#pragma unroll
      for (int j = 0; j < 3; j++)
        bfr[j] = *(const bf16x8*)&S[(64 + wn + j * 16 + l15) * 128 + csw];
#pragma unroll
      for (int mi = 0; mi < 2; mi++)
#pragma unroll
        for (int ni = 0; ni < 3; ni++)
          acc[mi * 3 + ni] = __builtin_amdgcn_mfma_f32_16x16x32_bf16(
              af[mi], bfr[ni], acc[mi * 3 + ni], 0, 0, 0);
    }
    __syncthreads();
  }
  float bv[3];
#pragma unroll
  for (int ni = 0; ni < 3; ni++) bv[ni] = bias[n0 + wn + ni * 16 + l15];
#pragma unroll
  for (int mi = 0; mi < 2; mi++)
#pragma unroll
    for (int ni = 0; ni < 3; ni++)
#pragma unroll
      for (int r = 0; r < 4; r++) {
        int grow = m0 + wm + mi * 16 + quad * 4 + r;
        int gcol = n0 + wn + ni * 16 + l15;
        out[(size_t)grow * CDIM + gcol] = acc[mi * 3 + ni][r] + bv[ni];
      }
}

extern "C" void kernel_launch(void* const* d_in, const int* in_sizes, int n_in,
                              void* d_out, int out_size, void* d_ws, size_t ws_size,
                              hipStream_t stream) {
  const float* xq = (const float*)d_in[0];
  const float* xk = (const float*)d_in[1];
  const float* xv = (const float*)d_in[2];
  const float* wq = (const float*)d_in[3];
  const float* wk = (const float*)d_in[4];
  const float* wv = (const float*)d_in[5];
  const float* wp = (const float*)d_in[6];
  const float* bp = (const float*)d_in[7];
  float* out = (float*)d_out;

  char* p = (char*)d_ws;
  unsigned short* Xq = (unsigned short*)p; p += (size_t)XEL * 2;
  unsigned short* Xk = (unsigned short*)p; p += (size_t)XEL * 2;
  unsigned short* Xv = (unsigned short*)p; p += (size_t)XEL * 2;
  unsigned short* Wq = (unsigned short*)p; p += (size_t)WEL * 2;
  unsigned short* Wk = (unsigned short*)p; p += (size_t)WEL * 2;
  unsigned short* Wv = (unsigned short*)p; p += (size_t)WEL * 2;
  unsigned short* Wp = (unsigned short*)p; p += (size_t)WEL * 2;
  unsigned short* Qb = (unsigned short*)p; p += (size_t)XEL * 2;
  unsigned short* Kb = (unsigned short*)p; p += (size_t)XEL * 2;
  unsigned short* Vb = (unsigned short*)p; p += (size_t)XEL * 2;
  unsigned short* Cx = (unsigned short*)p; p += (size_t)XEL * 2;

  cast_all<<<(3 * X8 + 4 * W8) / 256, 256, 0, stream>>>(
      xq, xk, xv, wq, wk, wv, wp, Xq, Xk, Xv, Wq, Wk, Wv, Wp);

  gemm_qkv<<<768, 256, 0, stream>>>(
      Xq, Xk, Xv, Wq, Wk, Wv, Qb, Kb, Vb);

  attn_kernel<<<768, 256, 0, stream>>>(Qb, Kb, Vb, Cx);

  gemm_out<<<512, 256, 0, stream>>>(Cx, Wp, bp, out);
}